// Round 10
// baseline (106.319 us; speedup 1.0000x reference)
//
#include <hip/hip_runtime.h>
#include <math.h>

constexpr int kNumSeqs      = 64;
constexpr int kNumHeads     = 32;
constexpr int kNumKVHeads   = 8;
constexpr int kHeadDim      = 128;
constexpr int kGQA          = 4;       // 32/8
constexpr int kKVBlock      = 16;
constexpr int kMaxSeqlen    = 1024;
constexpr int kBlocksPerSeq = 64;
constexpr int kChunk        = 64;      // positions per work item
constexpr int kMaxChunks    = kMaxSeqlen / kChunk;          // 16
constexpr int kNumSH        = kNumSeqs * kNumKVHeads;       // 512
constexpr float kScale      = 0.08838834764831845f;  // 1/sqrt(128)
constexpr float kEps        = 1e-6f;

// ws layout (float indices):
//   acc : [sh][chunk][g][128] -> 512*16*4*128 = 4,194,304 floats
//   m   : [sh][chunk][g]      -> 32,768
//   l   : [sh][chunk][g]      -> 32,768
constexpr size_t kAccElems = (size_t)kNumSH * kMaxChunks * kGQA * kHeadDim;
constexpr size_t kMOff     = kAccElems;
constexpr size_t kLOff     = kAccElems + (size_t)kNumSH * kMaxChunks * kGQA;

__launch_bounds__(256, 4)
__global__ void paged_attn_part(
    const float* __restrict__ q,
    const float* __restrict__ k,
    const float* __restrict__ v,
    const float* __restrict__ k_cache,
    const float* __restrict__ v_cache,
    const float* __restrict__ qw,
    const float* __restrict__ kw,
    const float* __restrict__ cos_cache,
    const float* __restrict__ sin_cache,
    const int*   __restrict__ position,
    const int*   __restrict__ block_tables,
    const int*   __restrict__ context_lens,
    float* __restrict__ ws)
{
  // item = (chunk, seq), chunk-major: always-live chunks 0..7 dispatch first.
  const int item = blockIdx.x;
  const int c    = item >> 6;            // chunk 0..15
  const int s    = item & 63;

  const int ctx = context_lens[s];
  const int n0  = c * kChunk;
  if (n0 >= ctx) return;                 // dead item: exit immediately

  const int tid  = threadIdx.x;
  const int wave = tid >> 6;
  const int lane = tid & 63;
  const int half = lane >> 5;            // which head of the wave's pair
  const int j    = lane & 31;            // dim group: floats [4j, 4j+4)
  const int hh   = wave * 2 + half;      // kv-head owned by this half-wave

  const int pos      = position[s];      // == ctx-1
  const int cnt      = min(n0 + kChunk, ctx) - n0;   // 1..64
  const int posLocal = pos - n0;
  const bool haspos  = (posLocal >= 0) && (posLocal < cnt);

  __shared__ __align__(16) float q_lds[kNumHeads][kHeadDim];     // 16 KB (normed+roped+scaled)
  __shared__ __align__(16) float kn_lds[kNumKVHeads][kHeadDim];  //  4 KB (new k)
  __shared__ __align__(16) float vn_lds[kNumKVHeads][kHeadDim];  //  4 KB (new v)
  __shared__ int bt_lds[kChunk / kKVBlock];                      //  4 entries

  // ---------------- prologue ----------------
  // lane-local RoPE/weight factors, shared by all heads this lane touches
  const float c0 = cos_cache[pos * 64 + j];
  const float c1 = cos_cache[pos * 64 + 32 + j];
  const float s0 = sin_cache[pos * 64 + j];
  const float s1 = sin_cache[pos * 64 + 32 + j];

  {
    const float w0 = qw[j], w1 = qw[j + 32], w2 = qw[j + 64], w3 = qw[j + 96];
    #pragma unroll
    for (int g = 0; g < kGQA; ++g) {
      const int qh = hh * kGQA + g;
      const float* qrow = q + (size_t)s * (kNumHeads * kHeadDim) + qh * kHeadDim;
      float x0 = qrow[j], x1 = qrow[j + 32], x2 = qrow[j + 64], x3 = qrow[j + 96];
      float ss = x0 * x0 + x1 * x1 + x2 * x2 + x3 * x3;
      #pragma unroll
      for (int off = 16; off >= 1; off >>= 1) ss += __shfl_xor(ss, off);
      const float r = rsqrtf(ss * (1.0f / kHeadDim) + kEps);
      x0 *= r * w0; x1 *= r * w1; x2 *= r * w2; x3 *= r * w3;
      q_lds[qh][j]      = (x0 * c0 - x2 * s0) * kScale;
      q_lds[qh][j + 32] = (x1 * c1 - x3 * s1) * kScale;
      q_lds[qh][j + 64] = (x2 * c0 + x0 * s0) * kScale;
      q_lds[qh][j + 96] = (x3 * c1 + x1 * s1) * kScale;
    }
  }
  if (haspos) {   // only the chunk containing pos needs the new k/v
    const float w0 = kw[j], w1 = kw[j + 32], w2 = kw[j + 64], w3 = kw[j + 96];
    const float* krow = k + (size_t)s * (kNumKVHeads * kHeadDim) + hh * kHeadDim;
    float x0 = krow[j], x1 = krow[j + 32], x2 = krow[j + 64], x3 = krow[j + 96];
    float ss = x0 * x0 + x1 * x1 + x2 * x2 + x3 * x3;
    #pragma unroll
    for (int off = 16; off >= 1; off >>= 1) ss += __shfl_xor(ss, off);
    const float r = rsqrtf(ss * (1.0f / kHeadDim) + kEps);
    x0 *= r * w0; x1 *= r * w1; x2 *= r * w2; x3 *= r * w3;
    kn_lds[hh][j]      = x0 * c0 - x2 * s0;
    kn_lds[hh][j + 32] = x1 * c1 - x3 * s1;
    kn_lds[hh][j + 64] = x2 * c0 + x0 * s0;
    kn_lds[hh][j + 96] = x3 * c1 + x1 * s1;
    const float* vrow = v + (size_t)s * (kNumKVHeads * kHeadDim) + hh * kHeadDim;
    *(float4*)&vn_lds[hh][4 * j] = *(const float4*)(vrow + 4 * j);
  }
  if (tid < kChunk / kKVBlock)
    bt_lds[tid] = block_tables[s * kBlocksPerSeq + c * (kChunk / kKVBlock) + tid];
  __syncthreads();   // B1 (only barrier)

  float4 qf[kGQA];
  #pragma unroll
  for (int g = 0; g < kGQA; ++g)
    qf[g] = *(const float4*)&q_lds[hh * kGQA + g][4 * j];
  const float4 knf = *(const float4*)&kn_lds[hh][4 * j];  // used only when haspos
  const float4 vnf = *(const float4*)&vn_lds[hh][4 * j];

  // ---------------- flash loop: 4 consecutive positions/batch ----------------
  // Wave loads 1 KB/instr (2 heads x 512 B); block covers full 4 KB rows;
  // a batch = 16 KB contiguous per block.
  float mrun[kGQA], lrun[kGQA];
  float4 acc[kGQA];
  #pragma unroll
  for (int g = 0; g < kGQA; ++g) {
    mrun[g] = -3.0e38f; lrun[g] = 0.0f;
    acc[g] = make_float4(0.f, 0.f, 0.f, 0.f);
  }

  const int nb = (cnt + 3) >> 2;
  for (int b = 0; b < nb; ++b) {
    float4 kv[4], vv[4];
    bool   val[4];
    int    pp4[4];
    #pragma unroll
    for (int jj = 0; jj < 4; ++jj) {
      const int p = 4 * b + jj;
      val[jj] = (p < cnt);
      const int pp = val[jj] ? p : (cnt - 1);
      pp4[jj] = pp;
      const int blk = bt_lds[pp >> 4];
      const size_t off =
          ((size_t)blk * kKVBlock + (pp & 15)) * (kNumKVHeads * kHeadDim) +
          hh * kHeadDim + 4 * j;
      kv[jj] = *(const float4*)(k_cache + off);
      vv[jj] = *(const float4*)(v_cache + off);
    }
    #pragma unroll
    for (int jj = 0; jj < 4; ++jj) {
      if (haspos && pp4[jj] == posLocal) { kv[jj] = knf; vv[jj] = vnf; }  // virtual insert
    }

    float sg[4][kGQA];
    #pragma unroll
    for (int jj = 0; jj < 4; ++jj) {
      #pragma unroll
      for (int g = 0; g < kGQA; ++g)
        sg[jj][g] = qf[g].x * kv[jj].x + qf[g].y * kv[jj].y +
                    qf[g].z * kv[jj].z + qf[g].w * kv[jj].w;
    }
    #pragma unroll
    for (int off = 16; off >= 1; off >>= 1) {   // reduce within 32-lane half-wave
      #pragma unroll
      for (int jj = 0; jj < 4; ++jj) {
        #pragma unroll
        for (int g = 0; g < kGQA; ++g) sg[jj][g] += __shfl_xor(sg[jj][g], off);
      }
    }
    #pragma unroll
    for (int jj = 0; jj < 4; ++jj) {
      if (!val[jj]) {
        #pragma unroll
        for (int g = 0; g < kGQA; ++g) sg[jj][g] = -3.0e38f;
      }
    }

    // online softmax update (per half-wave, replicated across its 32 lanes)
    #pragma unroll
    for (int g = 0; g < kGQA; ++g) {
      const float mb = fmaxf(fmaxf(sg[0][g], sg[1][g]), fmaxf(sg[2][g], sg[3][g]));
      const float mn = fmaxf(mrun[g], mb);
      const float f  = __expf(mrun[g] - mn);
      const float p0 = __expf(sg[0][g] - mn);
      const float p1 = __expf(sg[1][g] - mn);
      const float p2 = __expf(sg[2][g] - mn);
      const float p3 = __expf(sg[3][g] - mn);
      lrun[g] = lrun[g] * f + (p0 + p1 + p2 + p3);
      acc[g].x = acc[g].x * f + p0 * vv[0].x + p1 * vv[1].x + p2 * vv[2].x + p3 * vv[3].x;
      acc[g].y = acc[g].y * f + p0 * vv[0].y + p1 * vv[1].y + p2 * vv[2].y + p3 * vv[3].y;
      acc[g].z = acc[g].z * f + p0 * vv[0].z + p1 * vv[1].z + p2 * vv[2].z + p3 * vv[3].z;
      acc[g].w = acc[g].w * f + p0 * vv[0].w + p1 * vv[1].w + p2 * vv[2].w + p3 * vv[3].w;
      mrun[g] = mn;
    }
  }

  // ---------------- emit partials (no cross-wave merge needed) ----------------
  const int sh = s * kNumKVHeads + hh;
  float* accw = ws + ((size_t)sh * kMaxChunks + c) * (kGQA * kHeadDim);
  #pragma unroll
  for (int g = 0; g < kGQA; ++g)
    *(float4*)(accw + g * kHeadDim + 4 * j) = acc[g];
  if (j == 0) {
    float* mw = ws + kMOff + ((size_t)sh * kMaxChunks + c) * kGQA;
    float* lw = ws + kLOff + ((size_t)sh * kMaxChunks + c) * kGQA;
    #pragma unroll
    for (int g = 0; g < kGQA; ++g) { mw[g] = mrun[g]; lw[g] = lrun[g]; }
  }
}

__launch_bounds__(128)
__global__ void paged_attn_reduce(const float* __restrict__ ws,
                                  const int* __restrict__ context_lens,
                                  float* __restrict__ out)
{
  const int idx = blockIdx.x;          // sh*4 + g
  const int g   = idx & 3;
  const int sh  = idx >> 2;
  const int d   = threadIdx.x;
  const int s   = sh >> 3;
  const int h   = sh & 7;

  const int nch = (context_lens[s] + kChunk - 1) / kChunk;   // 8..16 live chunks

  const float* mw = ws + kMOff + (size_t)sh * (kMaxChunks * kGQA);
  const float* lw = ws + kLOff + (size_t)sh * (kMaxChunks * kGQA);

  float mstar = -3.0e38f;
  for (int p = 0; p < nch; ++p) mstar = fmaxf(mstar, mw[p * kGQA + g]);

  float lstar = 0.0f, o = 0.0f;
  for (int p = 0; p < nch; ++p) {
    const float w = __expf(mw[p * kGQA + g] - mstar);
    lstar += w * lw[p * kGQA + g];
    const float* accp =
        ws + ((size_t)sh * kMaxChunks + p) * (kGQA * kHeadDim) + (size_t)g * kHeadDim;
    o += w * accp[d];
  }
  out[(size_t)s * (kNumHeads * kHeadDim) + (h * kGQA + g) * kHeadDim + d] = o / lstar;
}

extern "C" void kernel_launch(void* const* d_in, const int* in_sizes, int n_in,
                              void* d_out, int out_size, void* d_ws, size_t ws_size,
                              hipStream_t stream) {
  const float* q            = (const float*)d_in[0];
  const float* k            = (const float*)d_in[1];
  const float* v            = (const float*)d_in[2];
  const float* k_cache      = (const float*)d_in[3];
  const float* v_cache      = (const float*)d_in[4];
  const float* qw           = (const float*)d_in[5];
  const float* kw           = (const float*)d_in[6];
  const float* cosc         = (const float*)d_in[7];
  const float* sinc         = (const float*)d_in[8];
  const int*   position     = (const int*)d_in[9];
  const int*   block_tables = (const int*)d_in[11];
  const int*   context_lens = (const int*)d_in[12];
  float* out                = (float*)d_out;
  float* ws                 = (float*)d_ws;

  hipLaunchKernelGGL(paged_attn_part, dim3(kMaxChunks * kNumSeqs), dim3(256), 0, stream,
                     q, k, v, k_cache, v_cache, qw, kw, cosc, sinc,
                     position, block_tables, context_lens, ws);
  hipLaunchKernelGGL(paged_attn_reduce, dim3(kNumSH * kGQA), dim3(kHeadDim), 0, stream,
                     ws, context_lens, out);
}